// Round 1
// baseline (6833.068 us; speedup 1.0000x reference)
//
#include <hip/hip_runtime.h>
#include <stdint.h>

typedef __bf16 bf16;
typedef bf16 bf16x8 __attribute__((ext_vector_type(8)));
typedef float f32x4 __attribute__((ext_vector_type(4)));

#define DEV __device__ __forceinline__

// ---------------- workspace layout (bytes) ----------------
// packed weights: [4H][K] bf16, column order: pc -> (nb=pc>>7, gate=(pc>>5)&3, u=(pc>>7)*32+(pc&31))
static const size_t OFF_W1 = 0;                                   // 1024*320*2
static const size_t OFF_W2 = OFF_W1 + (size_t)1024*320*2;
static const size_t OFF_W3 = OFF_W2 + (size_t)1024*320*2;         // 512*160*2
static const size_t OFF_B1 = OFF_W3 + (size_t)512*160*2;          // 1024 f32
static const size_t OFF_B2 = OFF_B1 + 4096;
static const size_t OFF_B3 = OFF_B2 + 4096;                       // 512 f32
static const size_t OFF_H1 = OFF_B3 + 2048;                       // 2*1024*256 bf16
static const size_t OFF_H2 = OFF_H1 + (size_t)2*1024*256*2;       // 2*512*256 bf16
static const size_t OFF_H3 = OFF_H2 + (size_t)2*512*256*2;        // 2*12288*128 bf16
static const size_t OFF_FEAT = OFF_H3 + (size_t)2*12288*128*2;    // 512*3840 f32
static const size_t OFF_CNT = OFF_FEAT + (size_t)512*3840*4;      // 120 counters, 64B apart
static const size_t WS_NEEDED = OFF_CNT + 120*64;

DEV float sigm(float x) { return 1.f / (1.f + __expf(-x)); }
DEV float tanh_(float x) { return 1.f - 2.f / (__expf(2.f * x) + 1.f); }

// ---------------- prep: pack weights bf16 + zero state ----------------
DEV void pack2(const float* Wih, const float* Whh, int Hh, int In, bf16* dst, int pc, int kk) {
  int gate = (pc >> 5) & 3;
  int u = ((pc >> 7) << 5) + (pc & 31);
  int orig = gate * Hh + u;
  int KT = In + Hh;
  float f0, f1;
  if (kk < In) { f0 = Wih[orig * In + kk]; f1 = Wih[orig * In + kk + 1]; }
  else         { f0 = Whh[orig * Hh + kk - In]; f1 = Whh[orig * Hh + kk - In + 1]; }
  dst[(size_t)pc * KT + kk]     = (bf16)f0;
  dst[(size_t)pc * KT + kk + 1] = (bf16)f1;
}

__global__ void prep_kernel(const float* __restrict__ Wih1, const float* __restrict__ Whh1,
                            const float* __restrict__ bih1, const float* __restrict__ bhh1,
                            const float* __restrict__ Wih2, const float* __restrict__ Whh2,
                            const float* __restrict__ bih2, const float* __restrict__ bhh2,
                            const float* __restrict__ Wih3, const float* __restrict__ Whh3,
                            const float* __restrict__ bih3, const float* __restrict__ bhh3,
                            uint8_t* __restrict__ ws) {
  const int gt = blockIdx.x * blockDim.x + threadIdx.x;
  const int gs = gridDim.x * blockDim.x;
  bf16* W1 = (bf16*)(ws + OFF_W1);
  bf16* W2 = (bf16*)(ws + OFF_W2);
  bf16* W3 = (bf16*)(ws + OFF_W3);
  for (int i = gt; i < 1024 * 160; i += gs) {
    int pc = i / 160, kk = (i % 160) * 2;
    pack2(Wih1, Whh1, 256, 64, W1, pc, kk);
    pack2(Wih2, Whh2, 256, 64, W2, pc, kk);
  }
  for (int i = gt; i < 512 * 80; i += gs) {
    int pc = i / 80, kk = (i % 80) * 2;
    pack2(Wih3, Whh3, 128, 32, W3, pc, kk);
  }
  for (int i = gt; i < 1024; i += gs) {
    int gate = (i >> 5) & 3;
    int u = ((i >> 7) << 5) + (i & 31);
    int orig = gate * 256 + u;
    ((float*)(ws + OFF_B1))[i] = bih1[orig] + bhh1[orig];
    ((float*)(ws + OFF_B2))[i] = bih2[orig] + bhh2[orig];
  }
  for (int i = gt; i < 512; i += gs) {
    int gate = (i >> 5) & 3;
    int u = ((i >> 7) << 5) + (i & 31);
    int orig = gate * 128 + u;
    ((float*)(ws + OFF_B3))[i] = bih3[orig] + bhh3[orig];
  }
  // zero h slot-1 (read at t=0) + barrier counters
  uint32_t* z1 = (uint32_t*)(ws + OFF_H1 + (size_t)1024 * 256 * 2);
  for (int i = gt; i < 1024 * 256 / 2; i += gs) z1[i] = 0;
  uint32_t* z2 = (uint32_t*)(ws + OFF_H2 + (size_t)512 * 256 * 2);
  for (int i = gt; i < 512 * 256 / 2; i += gs) z2[i] = 0;
  uint32_t* z3 = (uint32_t*)(ws + OFF_H3 + (size_t)12288 * 128 * 2);
  for (int i = gt; i < 12288 * 128 / 2; i += gs) z3[i] = 0;
  uint32_t* zc = (uint32_t*)(ws + OFF_CNT);
  for (int i = gt; i < 120 * 16; i += gs) zc[i] = 0;
}

// ---------------- persistent LSTM tile ----------------
// Block: 256 threads = 4 waves. Block owns BM rows x 32 units (128 gate-cols).
// Wave w owns gate-cols [w*32, w*32+32) = gate w of the block's 32 units (gate-major local cols).
// LDS: A = [BM][KTOT] bf16 (XOR-swizzled 16B chunks), overlaid by G = [128][64] f32 after GEMM.
// hst = [64][40] bf16 transpose stage.  Total 46080 B.
template <int BM, int IN, int H, int T, int NBLK, int MTOT, int DOM>
DEV void lstm_tile(const float* __restrict__ x0, const float* __restrict__ x1, int halfM,
                   const bf16* __restrict__ Wp, const float* __restrict__ bp,
                   bf16* __restrict__ hbuf, uint32_t* __restrict__ cnt,
                   float* __restrict__ feat, int mg, int nb, uint8_t* smem) {
  constexpr int KTOT = IN + H;
  constexpr int NKT = KTOT / 32;      // k-tiles of 32
  constexpr int NMT = BM / 16;        // m-tiles
  constexpr int KCH = KTOT / 8;       // 16B chunks per A row
  constexpr int SWZ = (KCH % 8 == 0) ? 7 : 3;
  constexpr int HP = BM / 64;         // half-passes through G/activation
  constexpr int NHC = BM * H / (8 * 256);  // h 16B-chunks per thread per step

  const int tid = threadIdx.x;
  const int lane = tid & 63;
  const int wav = tid >> 6;
  const int quad = lane >> 4;
  const int l16 = lane & 15;
  const int rowbase = mg * BM;

  bf16* A = (bf16*)smem;
  float* G = (float*)smem;
  bf16* hst = (bf16*)(smem + 40960);

  const float* xb = (rowbase < halfM) ? x0 : x1;
  const int rowoff = rowbase - ((rowbase < halfM) ? 0 : halfM);

  // preload W fragments (B-operand: lane holds W[pc][kt*32+quad*8 .. +7]) + bias
  bf16x8 wfr[2][NKT];
  float b2[2];
#pragma unroll
  for (int nt = 0; nt < 2; ++nt) {
    const int pc = nb * 128 + wav * 32 + nt * 16 + l16;
    b2[nt] = bp[pc];
#pragma unroll
    for (int kt = 0; kt < NKT; ++kt)
      wfr[nt][kt] = *(const bf16x8*)(Wp + (size_t)pc * KTOT + kt * 32 + quad * 8);
  }

  float creg[HP * 8];
#pragma unroll
  for (int i = 0; i < HP * 8; ++i) creg[i] = 0.f;

#pragma unroll 1
  for (int t = 0; t < T; ++t) {
    // ---- stage A = [x_t | h_{t-1}] ----
    {
      const bf16* hsrc = hbuf + (size_t)((t + 1) & 1) * MTOT * H;
#pragma unroll
      for (int i = 0; i < NHC; ++i) {
        int ch = i * 256 + tid;
        int row = ch / (H / 8);
        int uc = ch % (H / 8);
        uint4 v = *(const uint4*)(hsrc + (size_t)(rowbase + row) * H + uc * 8);
        int kc = (IN / 8 + uc) ^ (row & SWZ);
        *(uint4*)(A + row * KTOT + kc * 8) = v;
      }
      int row = tid / (IN / 16);
      int fo = (tid % (IN / 16)) * 16;
      const float* xs = xb + (size_t)(rowoff + row) * T * IN + (size_t)t * IN + fo;
      float4 f0 = *(const float4*)(xs);
      float4 f1 = *(const float4*)(xs + 4);
      float4 f2 = *(const float4*)(xs + 8);
      float4 f3 = *(const float4*)(xs + 12);
      bf16x8 p0, p1;
      p0[0] = (bf16)f0.x; p0[1] = (bf16)f0.y; p0[2] = (bf16)f0.z; p0[3] = (bf16)f0.w;
      p0[4] = (bf16)f1.x; p0[5] = (bf16)f1.y; p0[6] = (bf16)f1.z; p0[7] = (bf16)f1.w;
      p1[0] = (bf16)f2.x; p1[1] = (bf16)f2.y; p1[2] = (bf16)f2.z; p1[3] = (bf16)f2.w;
      p1[4] = (bf16)f3.x; p1[5] = (bf16)f3.y; p1[6] = (bf16)f3.z; p1[7] = (bf16)f3.w;
      int kb = fo / 8;
      *(bf16x8*)(A + row * KTOT + ((kb ^ (row & SWZ))) * 8) = p0;
      *(bf16x8*)(A + row * KTOT + (((kb + 1) ^ (row & SWZ))) * 8) = p1;
    }
    __syncthreads();

    // ---- GEMM: gates = A @ Wp^T ----
    f32x4 acc[2][NMT];
#pragma unroll
    for (int nt = 0; nt < 2; ++nt)
#pragma unroll
      for (int mt = 0; mt < NMT; ++mt) acc[nt][mt] = f32x4{0.f, 0.f, 0.f, 0.f};
#pragma unroll
    for (int kt = 0; kt < NKT; ++kt) {
      bf16x8 af[NMT];
#pragma unroll
      for (int mt = 0; mt < NMT; ++mt) {
        int row = mt * 16 + l16;
        int kc = (kt * 4 + quad) ^ (row & SWZ);
        af[mt] = *(const bf16x8*)(A + row * KTOT + kc * 8);
      }
#pragma unroll
      for (int nt = 0; nt < 2; ++nt)
#pragma unroll
        for (int mt = 0; mt < NMT; ++mt)
          acc[nt][mt] = __builtin_amdgcn_mfma_f32_16x16x32_bf16(af[mt], wfr[nt][kt], acc[nt][mt], 0, 0, 0);
    }
    __syncthreads();  // A dead -> G region writable

    // ---- per 64-row half: gate regroup + activation + h publish ----
#pragma unroll
    for (int hp = 0; hp < HP; ++hp) {
      // write gates (+bias) to G[c][row], 16B chunks swizzled by col
#pragma unroll
      for (int nt = 0; nt < 2; ++nt) {
        int c = wav * 32 + nt * 16 + l16;
#pragma unroll
        for (int mtl = 0; mtl < 4; ++mtl) {
          int mt = hp * 4 + mtl;
          int chunk = (mtl * 4 + quad) ^ (c & 7);
          f32x4 v = acc[nt][mt];
          v[0] += b2[nt]; v[1] += b2[nt]; v[2] += b2[nt]; v[3] += b2[nt];
          *(f32x4*)(G + c * 64 + chunk * 4) = v;
        }
      }
      __syncthreads();
      // activation: thread = (unit u, 8 rows)
      {
        int u = tid & 31;
        int rc = tid >> 5;
        float vi[8], vf[8], vg[8], vo[8];
#define LOADG(dst, gate)                                                              \
        {                                                                             \
          int c = (gate) * 32 + u;                                                    \
          f32x4 a = *(const f32x4*)(G + c * 64 + ((2 * rc) ^ (c & 7)) * 4);           \
          f32x4 b = *(const f32x4*)(G + c * 64 + ((2 * rc + 1) ^ (c & 7)) * 4);       \
          dst[0] = a[0]; dst[1] = a[1]; dst[2] = a[2]; dst[3] = a[3];                 \
          dst[4] = b[0]; dst[5] = b[1]; dst[6] = b[2]; dst[7] = b[3];                 \
        }
        LOADG(vi, 0) LOADG(vf, 1) LOADG(vg, 2) LOADG(vo, 3)
#undef LOADG
#pragma unroll
        for (int j = 0; j < 8; ++j) {
          float iv = sigm(vi[j]);
          float fv = sigm(vf[j]);
          float gv = tanh_(vg[j]);
          float ov = sigm(vo[j]);
          float cc = fv * creg[hp * 8 + j] + iv * gv;
          creg[hp * 8 + j] = cc;
          float hv = ov * tanh_(cc);
          hst[(rc * 8 + j) * 40 + u] = (bf16)hv;
          if (t == T - 1) {  // final hidden -> feat (fp32)
            int R = rowbase + hp * 64 + rc * 8 + j;
            int b, col;
            if (DOM == 0) {
              if (R < 512) { b = R; col = nb * 32 + u; }
              else         { b = R - 512; col = 256 + nb * 32 + u; }
            } else if (DOM == 1) {
              b = R; col = 512 + nb * 32 + u;
            } else {
              int rr = R; int base = 768;
              if (rr >= 6144) { rr -= 6144; base = 2304; }
              b = rr / 12; int p = rr - b * 12;
              col = base + p * 128 + nb * 32 + u;
            }
            feat[(size_t)b * 3840 + col] = hv;
          }
        }
      }
      __syncthreads();
      // publish h slice to global double-buffer
      if (t < T - 1) {
        int row = tid >> 2;
        int uc = tid & 3;
        uint4 v = *(const uint4*)(hst + row * 40 + uc * 8);
        bf16* hdst = hbuf + (size_t)(t & 1) * MTOT * H;
        *(uint4*)(hdst + (size_t)(rowbase + hp * 64 + row) * H + nb * 32 + uc * 8) = v;
      }
      __syncthreads();
    }

    // ---- per-group barrier (producers of these rows' h) ----
    if (t < T - 1) {
      if (tid == 0) {
        __threadfence();
        __hip_atomic_fetch_add(cnt, 1u, __ATOMIC_RELEASE, __HIP_MEMORY_SCOPE_AGENT);
        const uint32_t tgt = (uint32_t)(t + 1) * NBLK;
        while (__hip_atomic_load(cnt, __ATOMIC_ACQUIRE, __HIP_MEMORY_SCOPE_AGENT) < tgt)
          __builtin_amdgcn_s_sleep(1);
        __threadfence();
      }
      __syncthreads();
    }
  }
}

__global__ __launch_bounds__(256, 2) void lstm_main(const float* __restrict__ gh,
                                                    const float* __restrict__ ga,
                                                    const float* __restrict__ gv,
                                                    const float* __restrict__ ph,
                                                    const float* __restrict__ pa,
                                                    uint8_t* __restrict__ ws) {
  __shared__ uint4 smem_[46080 / 16];
  uint8_t* smem = (uint8_t*)smem_;
  float* feat = (float*)(ws + OFF_FEAT);
  uint32_t* cnts = (uint32_t*)(ws + OFF_CNT);
  int bid = blockIdx.x;
  if (bid < 128) {
    lstm_tile<64, 64, 256, 128, 8, 1024, 0>(gh, ga, 512, (const bf16*)(ws + OFF_W1),
        (const float*)(ws + OFF_B1), (bf16*)(ws + OFF_H1), cnts + (bid >> 3) * 16, feat,
        bid >> 3, bid & 7, smem);
  } else if (bid < 192) {
    int b = bid - 128;
    lstm_tile<64, 64, 256, 128, 8, 512, 1>(gv, gv, 512, (const bf16*)(ws + OFF_W2),
        (const float*)(ws + OFF_B2), (bf16*)(ws + OFF_H2), cnts + (16 + (b >> 3)) * 16, feat,
        b >> 3, b & 7, smem);
  } else {
    int b = bid - 192;
    lstm_tile<128, 32, 128, 64, 4, 12288, 2>(ph, pa, 6144, (const bf16*)(ws + OFF_W3),
        (const float*)(ws + OFF_B3), (bf16*)(ws + OFF_H3), cnts + (24 + (b >> 2)) * 16, feat,
        b >> 2, b & 3, smem);
  }
}

// ---------------- final FC: out = [feat | current_game] @ Wfc^T + bfc ----------------
__global__ void fc_kernel(const float* __restrict__ feat, const float* __restrict__ cg,
                          const float* __restrict__ Wfc, const float* __restrict__ bfc,
                          float* __restrict__ out) {
  int b = blockIdx.x, tid = threadIdx.x;
  float a0 = 0.f, a1 = 0.f;
  for (int c = tid; c < 3840; c += 256) {
    float f = feat[(size_t)b * 3840 + c];
    a0 += f * Wfc[c];
    a1 += f * Wfc[3872 + c];
  }
  if (tid < 32) {
    float f = cg[b * 32 + tid];
    a0 += f * Wfc[3840 + tid];
    a1 += f * Wfc[3872 + 3840 + tid];
  }
#pragma unroll
  for (int o = 32; o > 0; o >>= 1) {
    a0 += __shfl_down(a0, o);
    a1 += __shfl_down(a1, o);
  }
  __shared__ float red[8];
  int wv = tid >> 6;
  if ((tid & 63) == 0) { red[wv * 2] = a0; red[wv * 2 + 1] = a1; }
  __syncthreads();
  if (tid == 0) {
    out[b * 2 + 0] = red[0] + red[2] + red[4] + red[6] + bfc[0];
    out[b * 2 + 1] = red[1] + red[3] + red[5] + red[7] + bfc[1];
  }
}

extern "C" void kernel_launch(void* const* d_in, const int* in_sizes, int n_in, void* d_out,
                              int out_size, void* d_ws, size_t ws_size, hipStream_t stream) {
  const float* cg = (const float*)d_in[0];
  const float* gh = (const float*)d_in[1];
  const float* ga = (const float*)d_in[2];
  const float* gv = (const float*)d_in[3];
  const float* ph = (const float*)d_in[4];
  const float* pa = (const float*)d_in[5];
  const float* Wih1 = (const float*)d_in[6];
  const float* Whh1 = (const float*)d_in[7];
  const float* bih1 = (const float*)d_in[8];
  const float* bhh1 = (const float*)d_in[9];
  const float* Wih2 = (const float*)d_in[10];
  const float* Whh2 = (const float*)d_in[11];
  const float* bih2 = (const float*)d_in[12];
  const float* bhh2 = (const float*)d_in[13];
  const float* Wih3 = (const float*)d_in[14];
  const float* Whh3 = (const float*)d_in[15];
  const float* bih3 = (const float*)d_in[16];
  const float* bhh3 = (const float*)d_in[17];
  const float* Wfc = (const float*)d_in[18];
  const float* bfc = (const float*)d_in[19];
  uint8_t* ws = (uint8_t*)d_ws;
  if (ws_size < WS_NEEDED) return;  // workspace too small; fail loudly via validation

  hipLaunchKernelGGL(prep_kernel, dim3(512), dim3(256), 0, stream, Wih1, Whh1, bih1, bhh1,
                     Wih2, Whh2, bih2, bhh2, Wih3, Whh3, bih3, bhh3, ws);
  hipLaunchKernelGGL(lstm_main, dim3(576), dim3(256), 0, stream, gh, ga, gv, ph, pa, ws);
  hipLaunchKernelGGL(fc_kernel, dim3(512), dim3(256), 0, stream,
                     (const float*)(ws + OFF_FEAT), cg, Wfc, bfc, (float*)d_out);
}

// Round 2
// 2129.034 us; speedup vs baseline: 3.2095x; 3.2095x over previous
//
#include <hip/hip_runtime.h>
#include <stdint.h>

typedef __bf16 bf16;
typedef bf16 bf16x8 __attribute__((ext_vector_type(8)));
typedef bf16 bf16x4 __attribute__((ext_vector_type(4)));
typedef float f32x4 __attribute__((ext_vector_type(4)));

#define DEV __device__ __forceinline__

// ---------------- workspace layout (bytes) ----------------
// W blobs: per design, fragment blobs of 1KB, order [wave][nt][kt], within blob lane*16B.
static const size_t OFF_W1 = 0;                                  // 640 blobs * 1024
static const size_t OFF_W2 = OFF_W1 + (size_t)640 * 1024;        // 640 blobs
static const size_t OFF_W3 = OFF_W2 + (size_t)640 * 1024;        // 160 blobs
static const size_t OFF_B1 = OFF_W3 + (size_t)160 * 1024;        // 1024 f32 (orig order)
static const size_t OFF_B2 = OFF_B1 + 4096;
static const size_t OFF_B3 = OFF_B2 + 4096;                      // 512 f32
static const size_t OFF_FEAT = OFF_B3 + 2048;                    // 512*3840 f32
static const size_t WS_NEEDED = OFF_FEAT + (size_t)512 * 3840 * 4;

DEV float sigm(float x) { return 1.f / (1.f + __expf(-x)); }
DEV float tanh_(float x) { return 1.f - 2.f / (__expf(2.f * x) + 1.f); }

// ---------------- prep: pack weights into fragment blobs ----------------
template <int H, int IN, int NT, int NKT>
DEV void packW(const float* __restrict__ Wih, const float* __restrict__ Whh,
               bf16* __restrict__ dst, int i) {
  // i indexes [w][nt][kt][lane][e] flattened; dst[i] is the blob layout directly.
  int e = i & 7, lane = (i >> 3) & 63;
  int rest = i >> 9;
  int kt = rest % NKT; rest /= NKT;
  int nt = rest % NT;  int w = rest / NT;
  int quad = lane >> 4, l16 = lane & 15;
  constexpr int NTG = NT / 4, UW = NT * 4;
  int unit = w * UW + (nt % NTG) * 16 + l16;
  int g = nt / NTG;
  int r = g * H + unit;
  int k = kt * 32 + quad * 8 + e;
  float v = (k < IN) ? Wih[r * IN + k] : Whh[r * H + (k - IN)];
  dst[i] = (bf16)v;
}

__global__ void prep_kernel(const float* __restrict__ Wih1, const float* __restrict__ Whh1,
                            const float* __restrict__ bih1, const float* __restrict__ bhh1,
                            const float* __restrict__ Wih2, const float* __restrict__ Whh2,
                            const float* __restrict__ bih2, const float* __restrict__ bhh2,
                            const float* __restrict__ Wih3, const float* __restrict__ Whh3,
                            const float* __restrict__ bih3, const float* __restrict__ bhh3,
                            uint8_t* __restrict__ ws) {
  const int gt = blockIdx.x * blockDim.x + threadIdx.x;
  const int gs = gridDim.x * blockDim.x;
  bf16* W1 = (bf16*)(ws + OFF_W1);
  bf16* W2 = (bf16*)(ws + OFF_W2);
  bf16* W3 = (bf16*)(ws + OFF_W3);
  float* B1 = (float*)(ws + OFF_B1);
  float* B2 = (float*)(ws + OFF_B2);
  float* B3 = (float*)(ws + OFF_B3);
  for (int i = gt; i < 640 * 512; i += gs) {
    packW<256, 64, 16, 10>(Wih1, Whh1, W1, i);
    packW<256, 64, 16, 10>(Wih2, Whh2, W2, i);
  }
  for (int i = gt; i < 160 * 512; i += gs) packW<128, 32, 8, 5>(Wih3, Whh3, W3, i);
  for (int i = gt; i < 1024; i += gs) { B1[i] = bih1[i] + bhh1[i]; B2[i] = bih2[i] + bhh2[i]; }
  for (int i = gt; i < 512; i += gs) B3[i] = bih3[i] + bhh3[i];
}

// ---------------- persistent LSTM tile, zero inter-block comm ----------------
// Block = 256 thr = 4 waves, 1 block/CU (512 VGPR/wave). Block owns BM rows x ALL 4H gate
// cols; wave w owns units [w*UW, (w+1)*UW). h lives in LDS A = [x_t | h], never global.
// W: nt 0..NV-1 VGPR-resident, nt NV..NV+NL-1 LDS-resident, rest streamed from L2
// (constant addresses -> L2-hot), double-buffered per kt.
template <int BM, int IN, int H, int T, int NT, int NKT, int NV, int NL, int NS, int DOM>
DEV void lstm_tile2(const float* __restrict__ x0, const float* __restrict__ x1, int halfM,
                    const bf16* __restrict__ Wd, const float* __restrict__ bsum,
                    float* __restrict__ feat, int mg, uint8_t* smem) {
  static_assert(NV + NL + NS == NT, "split");
  static_assert(NL <= 1, "NL 0/1 only");
  constexpr int MT = BM / 16;
  constexpr int NTG = NT / 4;
  constexpr int UW = NT * 4;
  constexpr int KCH = (IN + H) / 8;
  constexpr int SROW = KCH + 1;      // +1 chunk pad: row stride 16B*(KCH+1) -> bank rotate
  constexpr int AROWE = SROW * 8;
  constexpr int NF4 = BM * IN / 4;
  constexpr int XPT = NF4 / 256;

  const int tid = threadIdx.x;
  const int lane = tid & 63;
  const int w = tid >> 6;
  const int quad = lane >> 4;
  const int l16 = lane & 15;
  const int rowbase = mg * BM;

  bf16* A = (bf16*)smem;
  bf16* Wshm = (bf16*)(smem + 21504);

  const float* xb = (rowbase < halfM) ? x0 : x1;
  const int rowoff = rowbase - ((rowbase < halfM) ? 0 : halfM);

  // zero h-region of A (x-region staged below; disjoint -> no race)
  {
    constexpr int HCH = KCH - IN / 8;
    for (int i = tid; i < BM * HCH * 4; i += 256) {
      int row = i / (HCH * 4), rem = i % (HCH * 4);
      int chunk = IN / 8 + rem / 4, d = rem % 4;
      ((uint32_t*)A)[row * SROW * 4 + chunk * 4 + d] = 0;
    }
  }
  // stage LDS-resident W frags
  if constexpr (NL > 0) {
    for (int idx = tid; idx < 4 * NL * NKT * 64; idx += 256) {
      int ln = idx & 63;
      int kt = (idx >> 6) % NKT;
      int rest = (idx >> 6) / NKT;
      int nl = rest % NL, w2 = rest / NL;
      int blob = (w2 * NT + NV + nl) * NKT + kt;
      *(bf16x8*)(Wshm + (size_t)((w2 * NL + nl) * NKT + kt) * 512 + ln * 8) =
          *(const bf16x8*)(Wd + (size_t)blob * 512 + ln * 8);
    }
  }
  // preload VGPR-resident W
  bf16x8 wreg[NV][NKT];
  {
    const bf16* Wv = Wd + (size_t)(w * NT) * NKT * 512 + lane * 8;
#pragma unroll
    for (int nt = 0; nt < NV; ++nt)
#pragma unroll
      for (int kt = 0; kt < NKT; ++kt)
        wreg[nt][kt] = *(const bf16x8*)(Wv + (size_t)(nt * NKT + kt) * 512);
  }
  const bf16* Wstream = Wd + (size_t)(w * NT + NV + NL) * NKT * 512 + lane * 8;

  // biases (per lane: its units, 4 gates)
  float bias[4][NTG];
#pragma unroll
  for (int g = 0; g < 4; ++g)
#pragma unroll
    for (int ut = 0; ut < NTG; ++ut)
      bias[g][ut] = bsum[g * H + w * UW + ut * 16 + l16];

  // streamed-frag double buffer: prologue loads kt=0 into parity 0
  bf16x8 sbuf[2][NS > 0 ? NS : 1];
  if constexpr (NS > 0) {
#pragma unroll
    for (int ns = 0; ns < NS; ++ns)
      sbuf[0][ns] = *(const bf16x8*)(Wstream + (size_t)(ns * NKT) * 512);
  }
  bf16x8 wldsbuf[2];

  // stage x(0)
  float4 xr[XPT];
#pragma unroll
  for (int i = 0; i < XPT; ++i) {
    int idx = i * 256 + tid;
    int row = idx / (IN / 4), c4 = idx % (IN / 4);
    xr[i] = *(const float4*)(xb + (size_t)(rowoff + row) * T * IN + c4 * 4);
  }
#pragma unroll
  for (int i = 0; i < XPT; ++i) {
    int idx = i * 256 + tid;
    int row = idx / (IN / 4), c4 = idx % (IN / 4);
    int k = c4 * 4;
    bf16x4 p;
    p[0] = (bf16)xr[i].x; p[1] = (bf16)xr[i].y; p[2] = (bf16)xr[i].z; p[3] = (bf16)xr[i].w;
    *(bf16x4*)(A + row * AROWE + (k >> 3) * 8 + (k & 7)) = p;
  }
  __syncthreads();
  if constexpr (NL > 0)
    wldsbuf[0] = *(const bf16x8*)(Wshm + (size_t)(w * NKT) * 512 + lane * 8);

  float c[MT * NTG * 4];
#pragma unroll
  for (int i = 0; i < MT * NTG * 4; ++i) c[i] = 0.f;

  f32x4 acc[NT][MT];
  bf16x8 afbuf[2][MT];

#pragma unroll 1
  for (int t = 0; t < T; ++t) {
#pragma unroll
    for (int nt = 0; nt < NT; ++nt)
#pragma unroll
      for (int mt = 0; mt < MT; ++mt) acc[nt][mt] = f32x4{0.f, 0.f, 0.f, 0.f};
    // A-fragments for kt=0
#pragma unroll
    for (int mt = 0; mt < MT; ++mt)
      afbuf[0][mt] = *(const bf16x8*)(A + (mt * 16 + l16) * AROWE + quad * 8);
    // prefetch x(t+1)
    if (t < T - 1) {
#pragma unroll
      for (int i = 0; i < XPT; ++i) {
        int idx = i * 256 + tid;
        int row = idx / (IN / 4), c4 = idx % (IN / 4);
        xr[i] = *(const float4*)(xb + (size_t)(rowoff + row) * T * IN + (size_t)(t + 1) * IN + c4 * 4);
      }
    }
    // K loop: MFMA + cross-step-pipelined weight streaming
#pragma unroll
    for (int kt = 0; kt < NKT; ++kt) {
      const int ktn = (kt + 1) % NKT;
      const int pc = kt & 1, pn = (kt + 1) & 1;
      if (kt + 1 < NKT) {
#pragma unroll
        for (int mt = 0; mt < MT; ++mt)
          afbuf[pn][mt] =
              *(const bf16x8*)(A + (mt * 16 + l16) * AROWE + ((kt + 1) * 4 + quad) * 8);
      }
      if constexpr (NS > 0) {
#pragma unroll
        for (int ns = 0; ns < NS; ++ns)
          sbuf[pn][ns] = *(const bf16x8*)(Wstream + (size_t)(ns * NKT + ktn) * 512);
      }
      if constexpr (NL > 0)
        wldsbuf[pn] = *(const bf16x8*)(Wshm + (size_t)(w * NKT + ktn) * 512 + lane * 8);
#pragma unroll
      for (int nt = 0; nt < NV; ++nt)
#pragma unroll
        for (int mt = 0; mt < MT; ++mt)
          acc[nt][mt] =
              __builtin_amdgcn_mfma_f32_16x16x32_bf16(afbuf[pc][mt], wreg[nt][kt], acc[nt][mt], 0, 0, 0);
      if constexpr (NL > 0) {
#pragma unroll
        for (int mt = 0; mt < MT; ++mt)
          acc[NV][mt] =
              __builtin_amdgcn_mfma_f32_16x16x32_bf16(afbuf[pc][mt], wldsbuf[pc], acc[NV][mt], 0, 0, 0);
      }
      if constexpr (NS > 0) {
#pragma unroll
        for (int ns = 0; ns < NS; ++ns)
#pragma unroll
          for (int mt = 0; mt < MT; ++mt)
            acc[NV + NL + ns][mt] = __builtin_amdgcn_mfma_f32_16x16x32_bf16(
                afbuf[pc][mt], sbuf[pc][ns], acc[NV + NL + ns][mt], 0, 0, 0);
      }
    }
    __syncthreads();  // all A(t) reads complete before h(t)/x(t+1) writes

    // in-register activation: lane holds i,f,g,o of cell (row=mt*16+quad*4+j,
    // unit=w*UW+ut*16+l16) at acc[g*NTG+ut][mt][j]
#pragma unroll
    for (int mt = 0; mt < MT; ++mt)
#pragma unroll
      for (int ut = 0; ut < NTG; ++ut)
#pragma unroll
        for (int j = 0; j < 4; ++j) {
          float gi = acc[0 * NTG + ut][mt][j] + bias[0][ut];
          float gf = acc[1 * NTG + ut][mt][j] + bias[1][ut];
          float gg = acc[2 * NTG + ut][mt][j] + bias[2][ut];
          float go = acc[3 * NTG + ut][mt][j] + bias[3][ut];
          int ci = (mt * NTG + ut) * 4 + j;
          float cc = sigm(gf) * c[ci] + sigm(gi) * tanh_(gg);
          c[ci] = cc;
          float hv = sigm(go) * tanh_(cc);
          int row = mt * 16 + quad * 4 + j;
          if (t < T - 1) {
            int k = IN + w * UW + ut * 16 + l16;
            A[row * AROWE + (k >> 3) * 8 + (k & 7)] = (bf16)hv;
          } else {
            int R = rowbase + row;
            int unit = w * UW + ut * 16 + l16;
            int b, col;
            if (DOM == 0) {
              if (R < 512) { b = R; col = unit; }
              else         { b = R - 512; col = 256 + unit; }
            } else if (DOM == 1) {
              b = R; col = 512 + unit;
            } else {
              int rr = R; int base = 768;
              if (rr >= 6144) { rr -= 6144; base = 2304; }
              b = rr / 12; int p = rr - b * 12;
              col = base + p * 128 + unit;
            }
            feat[(size_t)b * 3840 + col] = hv;
          }
        }
    // write x(t+1)
    if (t < T - 1) {
#pragma unroll
      for (int i = 0; i < XPT; ++i) {
        int idx = i * 256 + tid;
        int row = idx / (IN / 4), c4 = idx % (IN / 4);
        int k = c4 * 4;
        bf16x4 p;
        p[0] = (bf16)xr[i].x; p[1] = (bf16)xr[i].y; p[2] = (bf16)xr[i].z; p[3] = (bf16)xr[i].w;
        *(bf16x4*)(A + row * AROWE + (k >> 3) * 8 + (k & 7)) = p;
      }
    }
    __syncthreads();  // A(t+1) ready
  }
}

__global__ __launch_bounds__(256, 1) void lstm_main(const float* __restrict__ gh,
                                                    const float* __restrict__ ga,
                                                    const float* __restrict__ gv,
                                                    const float* __restrict__ ph,
                                                    const float* __restrict__ pa,
                                                    uint8_t* __restrict__ ws) {
  __shared__ uint4 smem_[62464 / 16];
  uint8_t* smem = (uint8_t*)smem_;
  float* feat = (float*)(ws + OFF_FEAT);
  int bid = blockIdx.x;
  if (bid < 64) {
    lstm_tile2<16, 64, 256, 128, 16, 10, 6, 1, 9, 0>(
        gh, ga, 512, (const bf16*)(ws + OFF_W1), (const float*)(ws + OFF_B1), feat, bid, smem);
  } else if (bid < 96) {
    lstm_tile2<16, 64, 256, 128, 16, 10, 6, 1, 9, 1>(
        gv, gv, 512, (const bf16*)(ws + OFF_W2), (const float*)(ws + OFF_B2), feat, bid - 64, smem);
  } else {
    lstm_tile2<64, 32, 128, 64, 8, 5, 8, 0, 0, 2>(
        ph, pa, 6144, (const bf16*)(ws + OFF_W3), (const float*)(ws + OFF_B3), feat, bid - 96, smem);
  }
}

// ---------------- final FC: out = [feat | current_game] @ Wfc^T + bfc ----------------
__global__ void fc_kernel(const float* __restrict__ feat, const float* __restrict__ cg,
                          const float* __restrict__ Wfc, const float* __restrict__ bfc,
                          float* __restrict__ out) {
  int b = blockIdx.x, tid = threadIdx.x;
  float a0 = 0.f, a1 = 0.f;
  for (int c = tid; c < 3840; c += 256) {
    float f = feat[(size_t)b * 3840 + c];
    a0 += f * Wfc[c];
    a1 += f * Wfc[3872 + c];
  }
  if (tid < 32) {
    float f = cg[b * 32 + tid];
    a0 += f * Wfc[3840 + tid];
    a1 += f * Wfc[3872 + 3840 + tid];
  }
#pragma unroll
  for (int o = 32; o > 0; o >>= 1) {
    a0 += __shfl_down(a0, o);
    a1 += __shfl_down(a1, o);
  }
  __shared__ float red[8];
  int wv = tid >> 6;
  if ((tid & 63) == 0) { red[wv * 2] = a0; red[wv * 2 + 1] = a1; }
  __syncthreads();
  if (tid == 0) {
    out[b * 2 + 0] = red[0] + red[2] + red[4] + red[6] + bfc[0];
    out[b * 2 + 1] = red[1] + red[3] + red[5] + red[7] + bfc[1];
  }
}

extern "C" void kernel_launch(void* const* d_in, const int* in_sizes, int n_in, void* d_out,
                              int out_size, void* d_ws, size_t ws_size, hipStream_t stream) {
  const float* cg = (const float*)d_in[0];
  const float* gh = (const float*)d_in[1];
  const float* ga = (const float*)d_in[2];
  const float* gv = (const float*)d_in[3];
  const float* ph = (const float*)d_in[4];
  const float* pa = (const float*)d_in[5];
  const float* Wih1 = (const float*)d_in[6];
  const float* Whh1 = (const float*)d_in[7];
  const float* bih1 = (const float*)d_in[8];
  const float* bhh1 = (const float*)d_in[9];
  const float* Wih2 = (const float*)d_in[10];
  const float* Whh2 = (const float*)d_in[11];
  const float* bih2 = (const float*)d_in[12];
  const float* bhh2 = (const float*)d_in[13];
  const float* Wih3 = (const float*)d_in[14];
  const float* Whh3 = (const float*)d_in[15];
  const float* bih3 = (const float*)d_in[16];
  const float* bhh3 = (const float*)d_in[17];
  const float* Wfc = (const float*)d_in[18];
  const float* bfc = (const float*)d_in[19];
  uint8_t* ws = (uint8_t*)d_ws;
  if (ws_size < WS_NEEDED) return;

  hipLaunchKernelGGL(prep_kernel, dim3(512), dim3(256), 0, stream, Wih1, Whh1, bih1, bhh1,
                     Wih2, Whh2, bih2, bhh2, Wih3, Whh3, bih3, bhh3, ws);
  hipLaunchKernelGGL(lstm_main, dim3(288), dim3(256), 0, stream, gh, ga, gv, ph, pa, ws);
  hipLaunchKernelGGL(fc_kernel, dim3(512), dim3(256), 0, stream,
                     (const float*)(ws + OFF_FEAT), cg, Wfc, bfc, (float*)d_out);
}

// Round 3
// 1927.892 us; speedup vs baseline: 3.5443x; 1.1043x over previous
//
#include <hip/hip_runtime.h>
#include <stdint.h>

typedef __bf16 bf16;
typedef bf16 bf16x8 __attribute__((ext_vector_type(8)));
typedef bf16 bf16x4 __attribute__((ext_vector_type(4)));
typedef float f32x4 __attribute__((ext_vector_type(4)));
typedef int i32x4 __attribute__((ext_vector_type(4)));

#define DEV __device__ __forceinline__

// ---------------- workspace layout (bytes) ----------------
// W blobs: per design, fragment blobs of 1KB, order [wave][nt][kt], within blob lane*16B.
static const size_t OFF_W1 = 0;                                  // 640 blobs * 1024
static const size_t OFF_W2 = OFF_W1 + (size_t)640 * 1024;        // 640 blobs
static const size_t OFF_W3 = OFF_W2 + (size_t)640 * 1024;        // 160 blobs
static const size_t OFF_B1 = OFF_W3 + (size_t)160 * 1024;        // 1024 f32 (orig order)
static const size_t OFF_B2 = OFF_B1 + 4096;
static const size_t OFF_B3 = OFF_B2 + 4096;                      // 512 f32
static const size_t OFF_FEAT = OFF_B3 + 2048;                    // 512*3840 f32
static const size_t WS_NEEDED = OFF_FEAT + (size_t)512 * 3840 * 4;

DEV float sigm(float x) { return 1.f / (1.f + __expf(-x)); }
DEV float tanh_(float x) { return 1.f - 2.f / (__expf(2.f * x) + 1.f); }

// MFMA via inline asm: acc pinned to AGPR ("+a"); weight operand from VGPR ("v")
// or AGPR ("a"). This frees the 256-entry arch-VGPR file (round-2 spilled at 450
// live regs) and lets W live in the otherwise-idle AGPR half of the unified file.
DEV void mfma_bv(f32x4& acc, i32x4 a, i32x4 b) {
  asm("v_mfma_f32_16x16x32_bf16 %0, %1, %2, %0" : "+a"(acc) : "v"(a), "v"(b));
}
DEV void mfma_ba(f32x4& acc, i32x4 a, i32x4 b) {
  asm("v_mfma_f32_16x16x32_bf16 %0, %1, %2, %0" : "+a"(acc) : "v"(a), "a"(b));
}

// ---------------- prep: pack weights into fragment blobs ----------------
template <int H, int IN, int NT, int NKT>
DEV void packW(const float* __restrict__ Wih, const float* __restrict__ Whh,
               bf16* __restrict__ dst, int i) {
  int e = i & 7, lane = (i >> 3) & 63;
  int rest = i >> 9;
  int kt = rest % NKT; rest /= NKT;
  int nt = rest % NT;  int w = rest / NT;
  int quad = lane >> 4, l16 = lane & 15;
  constexpr int NTG = NT / 4, UW = NT * 4;
  int unit = w * UW + (nt % NTG) * 16 + l16;
  int g = nt / NTG;
  int r = g * H + unit;
  int k = kt * 32 + quad * 8 + e;
  float v = (k < IN) ? Wih[r * IN + k] : Whh[r * H + (k - IN)];
  dst[i] = (bf16)v;
}

__global__ void prep_kernel(const float* __restrict__ Wih1, const float* __restrict__ Whh1,
                            const float* __restrict__ bih1, const float* __restrict__ bhh1,
                            const float* __restrict__ Wih2, const float* __restrict__ Whh2,
                            const float* __restrict__ bih2, const float* __restrict__ bhh2,
                            const float* __restrict__ Wih3, const float* __restrict__ Whh3,
                            const float* __restrict__ bih3, const float* __restrict__ bhh3,
                            uint8_t* __restrict__ ws) {
  const int gt = blockIdx.x * blockDim.x + threadIdx.x;
  const int gs = gridDim.x * blockDim.x;
  bf16* W1 = (bf16*)(ws + OFF_W1);
  bf16* W2 = (bf16*)(ws + OFF_W2);
  bf16* W3 = (bf16*)(ws + OFF_W3);
  float* B1 = (float*)(ws + OFF_B1);
  float* B2 = (float*)(ws + OFF_B2);
  float* B3 = (float*)(ws + OFF_B3);
  for (int i = gt; i < 640 * 512; i += gs) {
    packW<256, 64, 16, 10>(Wih1, Whh1, W1, i);
    packW<256, 64, 16, 10>(Wih2, Whh2, W2, i);
  }
  for (int i = gt; i < 160 * 512; i += gs) packW<128, 32, 8, 5>(Wih3, Whh3, W3, i);
  for (int i = gt; i < 1024; i += gs) { B1[i] = bih1[i] + bhh1[i]; B2[i] = bih2[i] + bhh2[i]; }
  for (int i = gt; i < 512; i += gs) B3[i] = bih3[i] + bhh3[i];
}

// ---------------- persistent LSTM tile, zero inter-block comm ----------------
// Block = 256 thr = 4 waves, 1 block/CU. Block owns BM rows x ALL 4H gate cols; wave w
// owns units [w*UW,(w+1)*UW). h lives in LDS A=[x_t|h]. W classes by nt position:
// [0,NVV) VGPR-resident, [NVV,NVV+NVA) AGPR-resident, then NL LDS-resident, rest
// streamed from L2 (per-XCD L2 holds all W permanently), double-buffered per kt.
template <int BM, int IN, int H, int T, int NT, int NKT, int NVV, int NVA, int NL, int NS,
          int DOM>
DEV void lstm_tile3(const float* __restrict__ x0, const float* __restrict__ x1, int halfM,
                    const bf16* __restrict__ Wd, const float* __restrict__ bsum,
                    float* __restrict__ feat, int mg, uint8_t* smem) {
  static_assert(NVV + NVA + NL + NS == NT, "split");
  static_assert((NL == 0 && NS == 0) || (NKT % 2 == 0), "wrap parity");
  constexpr int MT = BM / 16;
  constexpr int NTG = NT / 4;
  constexpr int UW = NT * 4;
  constexpr int KCH = (IN + H) / 8;
  constexpr int SROW = KCH + 1;      // +1 chunk pad -> bank rotate per row
  constexpr int AROWE = SROW * 8;
  constexpr int XPT = BM * IN / 4 / 256;

  const int tid = threadIdx.x;
  const int lane = tid & 63;
  const int w = tid >> 6;
  const int quad = lane >> 4;
  const int l16 = lane & 15;
  const int rowbase = mg * BM;

  bf16* A = (bf16*)smem;
  bf16* Wshm = (bf16*)(smem + (size_t)BM * AROWE * 2);

  const float* xb = (rowbase < halfM) ? x0 : x1;
  const int rowoff = rowbase - ((rowbase < halfM) ? 0 : halfM);

  // zero h-region of A
  {
    constexpr int HCH = KCH - IN / 8;
    for (int i = tid; i < BM * HCH * 4; i += 256) {
      int row = i / (HCH * 4), rem = i % (HCH * 4);
      int chunk = IN / 8 + rem / 4, d = rem % 4;
      ((uint32_t*)A)[row * SROW * 4 + chunk * 4 + d] = 0;
    }
  }
  // stage LDS-resident W frags
  if constexpr (NL > 0) {
    for (int idx = tid; idx < 4 * NL * NKT * 64; idx += 256) {
      int ln = idx & 63;
      int kt = (idx >> 6) % NKT;
      int rest = (idx >> 6) / NKT;
      int nl = rest % NL, w2 = rest / NL;
      int blob = (w2 * NT + NVV + NVA + nl) * NKT + kt;
      *(bf16x8*)(Wshm + (size_t)((w2 * NL + nl) * NKT + kt) * 512 + ln * 8) =
          *(const bf16x8*)(Wd + (size_t)blob * 512 + ln * 8);
    }
  }
  // VGPR-resident W
  i32x4 wregv[NVV > 0 ? NVV : 1][NKT];
  {
    const bf16* Wv = Wd + (size_t)(w * NT) * NKT * 512 + lane * 8;
#pragma unroll
    for (int nt = 0; nt < NVV; ++nt)
#pragma unroll
      for (int kt = 0; kt < NKT; ++kt)
        wregv[nt][kt] = *(const i32x4*)(Wv + (size_t)(nt * NKT + kt) * 512);
  }
  // AGPR-resident W (all uses via "a" asm constraint -> allocator places in AGPRs)
  i32x4 wrega[NVA > 0 ? NVA : 1][NKT];
  {
    const bf16* Wa = Wd + (size_t)(w * NT + NVV) * NKT * 512 + lane * 8;
#pragma unroll
    for (int nt = 0; nt < NVA; ++nt)
#pragma unroll
      for (int kt = 0; kt < NKT; ++kt)
        wrega[nt][kt] = *(const i32x4*)(Wa + (size_t)(nt * NKT + kt) * 512);
  }
  const bf16* Wstream = Wd + (size_t)(w * NT + NVV + NVA + NL) * NKT * 512 + lane * 8;

  // biases
  float bias[4][NTG];
#pragma unroll
  for (int g = 0; g < 4; ++g)
#pragma unroll
    for (int ut = 0; ut < NTG; ++ut)
      bias[g][ut] = bsum[g * H + w * UW + ut * 16 + l16];

  i32x4 sbuf[2][NS > 0 ? NS : 1];
  i32x4 wlds[2][NL > 0 ? NL : 1];

  // stage x(0)
  float4 xr[XPT];
#pragma unroll
  for (int i = 0; i < XPT; ++i) {
    int idx = i * 256 + tid;
    int row = idx / (IN / 4), c4 = idx % (IN / 4);
    xr[i] = *(const float4*)(xb + (size_t)(rowoff + row) * T * IN + c4 * 4);
  }
#pragma unroll
  for (int i = 0; i < XPT; ++i) {
    int idx = i * 256 + tid;
    int row = idx / (IN / 4), c4 = idx % (IN / 4);
    int k = c4 * 4;
    bf16x4 p;
    p[0] = (bf16)xr[i].x; p[1] = (bf16)xr[i].y; p[2] = (bf16)xr[i].z; p[3] = (bf16)xr[i].w;
    *(bf16x4*)(A + row * AROWE + (k >> 3) * 8 + (k & 7)) = p;
  }
  __syncthreads();
  if constexpr (NS > 0) {
#pragma unroll
    for (int ns = 0; ns < NS; ++ns)
      sbuf[0][ns] = *(const i32x4*)(Wstream + (size_t)(ns * NKT) * 512);
  }
  if constexpr (NL > 0) {
#pragma unroll
    for (int nl = 0; nl < NL; ++nl)
      wlds[0][nl] = *(const i32x4*)(Wshm + (size_t)((w * NL + nl) * NKT) * 512 + lane * 8);
  }

  float c[MT * NTG * 4];
#pragma unroll
  for (int i = 0; i < MT * NTG * 4; ++i) c[i] = 0.f;

  f32x4 acc[NT][MT];
#pragma unroll
  for (int nt = 0; nt < NT; ++nt)
#pragma unroll
    for (int mt = 0; mt < MT; ++mt) acc[nt][mt] = f32x4{0.f, 0.f, 0.f, 0.f};

  i32x4 afbuf[2][MT];

#pragma unroll 1
  for (int t = 0; t < T; ++t) {
    // A-fragments for kt=0
#pragma unroll
    for (int mt = 0; mt < MT; ++mt)
      afbuf[0][mt] = *(const i32x4*)(A + (mt * 16 + l16) * AROWE + quad * 8);
    // prefetch x(t+1) (long-latency, overlaps whole K loop)
    if (t < T - 1) {
#pragma unroll
      for (int i = 0; i < XPT; ++i) {
        int idx = i * 256 + tid;
        int row = idx / (IN / 4), c4 = idx % (IN / 4);
        xr[i] =
            *(const float4*)(xb + (size_t)(rowoff + row) * T * IN + (size_t)(t + 1) * IN + c4 * 4);
      }
    }
    // K loop
#pragma unroll
    for (int kt = 0; kt < NKT; ++kt) {
      const int ktn = (kt + 1) % NKT;
      const int pc = kt & 1, pn = (kt + 1) & 1;
      if (kt + 1 < NKT) {
#pragma unroll
        for (int mt = 0; mt < MT; ++mt)
          afbuf[pn][mt] = *(const i32x4*)(A + (mt * 16 + l16) * AROWE + ((kt + 1) * 4 + quad) * 8);
      }
      if constexpr (NS > 0) {
#pragma unroll
        for (int ns = 0; ns < NS; ++ns)
          sbuf[pn][ns] = *(const i32x4*)(Wstream + (size_t)(ns * NKT + ktn) * 512);
      }
      if constexpr (NL > 0) {
#pragma unroll
        for (int nl = 0; nl < NL; ++nl)
          wlds[pn][nl] = *(const i32x4*)(Wshm + (size_t)((w * NL + nl) * NKT + ktn) * 512 + lane * 8);
      }
      // resident classes first; streamed last (max vmcnt slack, late acc writes)
#pragma unroll
      for (int nt = 0; nt < NVV; ++nt)
#pragma unroll
        for (int mt = 0; mt < MT; ++mt) mfma_bv(acc[nt][mt], afbuf[pc][mt], wregv[nt][kt]);
#pragma unroll
      for (int nt = 0; nt < NVA; ++nt)
#pragma unroll
        for (int mt = 0; mt < MT; ++mt) mfma_ba(acc[NVV + nt][mt], afbuf[pc][mt], wrega[nt][kt]);
      if constexpr (NL > 0) {
#pragma unroll
        for (int nl = 0; nl < NL; ++nl)
#pragma unroll
          for (int mt = 0; mt < MT; ++mt)
            mfma_bv(acc[NVV + NVA + nl][mt], afbuf[pc][mt], wlds[pc][nl]);
      }
      if constexpr (NS > 0) {
#pragma unroll
        for (int ns = 0; ns < NS; ++ns)
#pragma unroll
          for (int mt = 0; mt < MT; ++mt)
            mfma_bv(acc[NVV + NVA + NL + ns][mt], afbuf[pc][mt], sbuf[pc][ns]);
      }
    }
    __syncthreads();  // all A(t) reads done; also separates MFMA writes from acc reads
    asm volatile("s_nop 7\n\ts_nop 7\n\ts_nop 7" ::);  // MFMA->v_accvgpr_read hazard pad

    // in-register activation: lane holds i,f,g,o of cell (row=mt*16+quad*4+j,
    // unit=w*UW+ut*16+l16) at acc[g*NTG+ut][mt][j]
#pragma unroll
    for (int mt = 0; mt < MT; ++mt)
#pragma unroll
      for (int ut = 0; ut < NTG; ++ut)
#pragma unroll
        for (int j = 0; j < 4; ++j) {
          float gi = acc[0 * NTG + ut][mt][j] + bias[0][ut];
          float gf = acc[1 * NTG + ut][mt][j] + bias[1][ut];
          float gg = acc[2 * NTG + ut][mt][j] + bias[2][ut];
          float go = acc[3 * NTG + ut][mt][j] + bias[3][ut];
          int ci = (mt * NTG + ut) * 4 + j;
          float cc = sigm(gf) * c[ci] + sigm(gi) * tanh_(gg);
          c[ci] = cc;
          float hv = sigm(go) * tanh_(cc);
          int row = mt * 16 + quad * 4 + j;
          if (t < T - 1) {
            int k = IN + w * UW + ut * 16 + l16;
            A[row * AROWE + (k >> 3) * 8 + (k & 7)] = (bf16)hv;
          } else {
            int R = rowbase + row;
            int unit = w * UW + ut * 16 + l16;
            int b, col;
            if (DOM == 0) {
              if (R < 512) { b = R; col = unit; }
              else         { b = R - 512; col = 256 + unit; }
            } else if (DOM == 1) {
              b = R; col = 512 + unit;
            } else {
              int rr = R; int base = 768;
              if (rr >= 6144) { rr -= 6144; base = 2304; }
              b = rr / 12; int p = rr - b * 12;
              col = base + p * 128 + unit;
            }
            feat[(size_t)b * 3840 + col] = hv;
          }
        }
    // re-zero acc for next step HERE (VALU writes stay before the barrier ->
    // safe distance from next step's first MFMA srcC read)
#pragma unroll
    for (int nt = 0; nt < NT; ++nt)
#pragma unroll
      for (int mt = 0; mt < MT; ++mt) acc[nt][mt] = f32x4{0.f, 0.f, 0.f, 0.f};
    // write x(t+1)
    if (t < T - 1) {
#pragma unroll
      for (int i = 0; i < XPT; ++i) {
        int idx = i * 256 + tid;
        int row = idx / (IN / 4), c4 = idx % (IN / 4);
        int k = c4 * 4;
        bf16x4 p;
        p[0] = (bf16)xr[i].x; p[1] = (bf16)xr[i].y; p[2] = (bf16)xr[i].z; p[3] = (bf16)xr[i].w;
        *(bf16x4*)(A + row * AROWE + (k >> 3) * 8 + (k & 7)) = p;
      }
    }
    __syncthreads();
  }
}

template <int NL1, int NS1>
DEV void lstm_body(const float* gh, const float* ga, const float* gv, const float* ph,
                   const float* pa, uint8_t* ws, uint8_t* smem) {
  float* feat = (float*)(ws + OFF_FEAT);
  int bid = blockIdx.x;
  if (bid < 64) {
    lstm_tile3<16, 64, 256, 128, 16, 10, 2, 4, NL1, NS1, 0>(
        gh, ga, 512, (const bf16*)(ws + OFF_W1), (const float*)(ws + OFF_B1), feat, bid, smem);
  } else if (bid < 96) {
    lstm_tile3<16, 64, 256, 128, 16, 10, 2, 4, NL1, NS1, 1>(
        gv, gv, 512, (const bf16*)(ws + OFF_W2), (const float*)(ws + OFF_B2), feat, bid - 64, smem);
  } else {
    lstm_tile3<64, 32, 128, 64, 8, 5, 3, 5, 0, 0, 2>(
        ph, pa, 6144, (const bf16*)(ws + OFF_W3), (const float*)(ws + OFF_B3), feat, bid - 96, smem);
  }
}

__global__ __launch_bounds__(256, 1) void lstm_main_big(const float* __restrict__ gh,
                                                        const float* __restrict__ ga,
                                                        const float* __restrict__ gv,
                                                        const float* __restrict__ ph,
                                                        const float* __restrict__ pa,
                                                        uint8_t* __restrict__ ws) {
  extern __shared__ uint8_t smem[];
  lstm_body<2, 8>(gh, ga, gv, ph, pa, ws, smem);  // LDS: 10496 + 2*40960 = 92416
}

__global__ __launch_bounds__(256, 1) void lstm_main_small(const float* __restrict__ gh,
                                                          const float* __restrict__ ga,
                                                          const float* __restrict__ gv,
                                                          const float* __restrict__ ph,
                                                          const float* __restrict__ pa,
                                                          uint8_t* __restrict__ ws) {
  extern __shared__ uint8_t smem[];
  lstm_body<1, 9>(gh, ga, gv, ph, pa, ws, smem);  // LDS: 10496 + 40960 = 51456
}

// ---------------- final FC ----------------
__global__ void fc_kernel(const float* __restrict__ feat, const float* __restrict__ cg,
                          const float* __restrict__ Wfc, const float* __restrict__ bfc,
                          float* __restrict__ out) {
  int b = blockIdx.x, tid = threadIdx.x;
  float a0 = 0.f, a1 = 0.f;
  for (int c = tid; c < 3840; c += 256) {
    float f = feat[(size_t)b * 3840 + c];
    a0 += f * Wfc[c];
    a1 += f * Wfc[3872 + c];
  }
  if (tid < 32) {
    float f = cg[b * 32 + tid];
    a0 += f * Wfc[3840 + tid];
    a1 += f * Wfc[3872 + 3840 + tid];
  }
#pragma unroll
  for (int o = 32; o > 0; o >>= 1) {
    a0 += __shfl_down(a0, o);
    a1 += __shfl_down(a1, o);
  }
  __shared__ float red[8];
  int wv = tid >> 6;
  if ((tid & 63) == 0) { red[wv * 2] = a0; red[wv * 2 + 1] = a1; }
  __syncthreads();
  if (tid == 0) {
    out[b * 2 + 0] = red[0] + red[2] + red[4] + red[6] + bfc[0];
    out[b * 2 + 1] = red[1] + red[3] + red[5] + red[7] + bfc[1];
  }
}

extern "C" void kernel_launch(void* const* d_in, const int* in_sizes, int n_in, void* d_out,
                              int out_size, void* d_ws, size_t ws_size, hipStream_t stream) {
  const float* cg = (const float*)d_in[0];
  const float* gh = (const float*)d_in[1];
  const float* ga = (const float*)d_in[2];
  const float* gv = (const float*)d_in[3];
  const float* ph = (const float*)d_in[4];
  const float* pa = (const float*)d_in[5];
  const float* Wih1 = (const float*)d_in[6];
  const float* Whh1 = (const float*)d_in[7];
  const float* bih1 = (const float*)d_in[8];
  const float* bhh1 = (const float*)d_in[9];
  const float* Wih2 = (const float*)d_in[10];
  const float* Whh2 = (const float*)d_in[11];
  const float* bih2 = (const float*)d_in[12];
  const float* bhh2 = (const float*)d_in[13];
  const float* Wih3 = (const float*)d_in[14];
  const float* Whh3 = (const float*)d_in[15];
  const float* bih3 = (const float*)d_in[16];
  const float* bhh3 = (const float*)d_in[17];
  const float* Wfc = (const float*)d_in[18];
  const float* bfc = (const float*)d_in[19];
  uint8_t* ws = (uint8_t*)d_ws;
  if (ws_size < WS_NEEDED) return;

  hipLaunchKernelGGL(prep_kernel, dim3(512), dim3(256), 0, stream, Wih1, Whh1, bih1, bhh1,
                     Wih2, Whh2, bih2, bhh2, Wih3, Whh3, bih3, bhh3, ws);

  int dev = 0, maxShm = 0;
  (void)hipGetDevice(&dev);
  (void)hipDeviceGetAttribute(&maxShm, hipDeviceAttributeMaxSharedMemoryPerBlock, dev);
  hipError_t ae = hipFuncSetAttribute((const void*)lstm_main_big,
                                      hipFuncAttributeMaxDynamicSharedMemorySize, 92416);
  if (ae == hipSuccess && maxShm >= 92416) {
    hipLaunchKernelGGL(lstm_main_big, dim3(288), dim3(256), 92416, stream, gh, ga, gv, ph, pa, ws);
  } else {
    hipLaunchKernelGGL(lstm_main_small, dim3(288), dim3(256), 51456, stream, gh, ga, gv, ph, pa,
                       ws);
  }
  hipLaunchKernelGGL(fc_kernel, dim3(512), dim3(256), 0, stream,
                     (const float*)(ws + OFF_FEAT), cg, Wfc, bfc, (float*)d_out);
}